// Round 8
// baseline (1190.290 us; speedup 1.0000x reference)
//
// SelfAttention6 — MI355X bf16 MFMA, round 8:
//  - attn: exact round-4 (verified 137us: 64-key tiles, defer-max, batch->XCD)
//  - NEW gemm256 for FF1/FF2: 256-row tiles, 512 thr (8 waves 2x4), BK=32,
//    3-buffer rolling prefetch with COUNTED vmcnt (never drains mid-loop),
//    raw s_barrier + sched_barrier fences. QKV/W0 keep verified 128^2 kernel.
// B=64 S=1024 H=512 A=256 F=2048 NCATE=4 VOCAB=1000 EMB=64 NCONT=4
#include <hip/hip_runtime.h>

typedef unsigned short ushort_t;
typedef unsigned int uint32;
typedef float f32x4 __attribute__((ext_vector_type(4)));
typedef short bf16x8 __attribute__((ext_vector_type(8)));

// ---------- helpers ----------
__device__ __forceinline__ float bf2f(short u) {
  union { uint32 u32; float f; } cv;
  cv.u32 = ((uint32)(ushort_t)u) << 16;
  return cv.f;
}
__device__ __forceinline__ ushort_t f2bf(float f) {
  union { float f; uint32 u; } cv; cv.f = f;
  return (ushort_t)((cv.u + 0x7fffu + ((cv.u >> 16) & 1u)) >> 16);  // RNE
}
__device__ __forceinline__ uint32 pack2bf(float lo, float hi) {
  return (uint32)f2bf(lo) | ((uint32)f2bf(hi) << 16);
}
__device__ __forceinline__ f32x4 mfma16(bf16x8 a, bf16x8 b, f32x4 c) {
  return __builtin_amdgcn_mfma_f32_16x16x32_bf16(a, b, c, 0, 0, 0);
}
__device__ __forceinline__ void gld_lds16(const ushort_t* g, ushort_t* l) {
  __builtin_amdgcn_global_load_lds(
      (const __attribute__((address_space(1))) void*)g,
      (__attribute__((address_space(3))) void*)l, 16, 0, 0);
}

// ---------- weight transpose+cast: W[K][N] f32 -> WT[N][K] bf16 ----------
__global__ __launch_bounds__(256)
void transpose_w(const float* __restrict__ W, ushort_t* __restrict__ WT, int K, int N) {
  __shared__ float s[32][33];
  const int tx = threadIdx.x & 31, ty = threadIdx.x >> 5;
  const int k0 = blockIdx.x * 32, n0 = blockIdx.y * 32;
#pragma unroll
  for (int i = 0; i < 4; ++i)
    s[ty + i * 8][tx] = W[(size_t)(k0 + ty + i * 8) * N + n0 + tx];
  __syncthreads();
#pragma unroll
  for (int i = 0; i < 4; ++i)
    WT[(size_t)(n0 + ty + i * 8) * K + k0 + tx] = f2bf(s[tx][ty + i * 8]);
}

// ---------- EP[c,v,h] = sum_e E[c,v,e]*Wp[c*64+e, h]  (bf16 out) ----------
__global__ __launch_bounds__(256)
void ep_kernel(const float* __restrict__ E, const float* __restrict__ Wp,
               ushort_t* __restrict__ EP) {
  const int cv = blockIdx.x;          // 0..3999
  const int c = cv / 1000;
  __shared__ float se[64];
  if (threadIdx.x < 64) se[threadIdx.x] = E[(size_t)cv * 64 + threadIdx.x];
  __syncthreads();
  const float* wrow = Wp + (size_t)c * 64 * 512;
  for (int h = threadIdx.x; h < 512; h += 256) {
    float acc = 0.f;
#pragma unroll
    for (int e = 0; e < 64; ++e) acc += se[e] * wrow[(size_t)e * 512 + h];
    EP[(size_t)cv * 512 + h] = f2bf(acc);
  }
}

// ---------- positional-encoding table PE[1024][512] f32 ----------
__global__ __launch_bounds__(256)
void pe_kernel(float* __restrict__ PE) {
  const int id = blockIdx.x * 256 + threadIdx.x;  // 262144
  const int s = id >> 8, i = id & 255;
  const float ang = (float)s * exp2f(-(float)i * (13.287712379549449f / 256.0f));
  PE[(size_t)s * 512 + 2 * i] = sinf(ang);
  PE[(size_t)s * 512 + 2 * i + 1] = cosf(ang);
}

// ---------- x = gather(EP) + cont@Wp_tail + PE  -> bf16 [65536][512] ----------
__global__ __launch_bounds__(256)
void x_kernel(const int* __restrict__ cate, const float* __restrict__ cont,
              const float* __restrict__ Wp, const ushort_t* __restrict__ EP,
              const float* __restrict__ PE, ushort_t* __restrict__ X) {
  const int tid = threadIdx.x;
  const size_t r = (size_t)blockIdx.x * 4 + (tid >> 6);
  const int lane = tid & 63;
  const int h0 = lane * 8;
  const int s = (int)(r & 1023);
  float acc[8];
  const float4 p0 = *(const float4*)(PE + (size_t)s * 512 + h0);
  const float4 p1 = *(const float4*)(PE + (size_t)s * 512 + h0 + 4);
  acc[0] = p0.x; acc[1] = p0.y; acc[2] = p0.z; acc[3] = p0.w;
  acc[4] = p1.x; acc[5] = p1.y; acc[6] = p1.z; acc[7] = p1.w;
#pragma unroll
  for (int c = 0; c < 4; ++c) {
    const int idx = cate[r * 4 + c];
    const bf16x8 e8 = *(const bf16x8*)(EP + ((size_t)(c * 1000 + idx)) * 512 + h0);
#pragma unroll
    for (int k = 0; k < 8; ++k) acc[k] += bf2f(e8[k]);
  }
#pragma unroll
  for (int j = 0; j < 4; ++j) {
    const float cj = cont[r * 4 + j];
    const float4 w0 = *(const float4*)(Wp + (size_t)(256 + j) * 512 + h0);
    const float4 w1 = *(const float4*)(Wp + (size_t)(256 + j) * 512 + h0 + 4);
    acc[0] += cj * w0.x; acc[1] += cj * w0.y; acc[2] += cj * w0.z; acc[3] += cj * w0.w;
    acc[4] += cj * w1.x; acc[5] += cj * w1.y; acc[6] += cj * w1.z; acc[7] += cj * w1.w;
  }
  bf16x8 ov;
#pragma unroll
  for (int k = 0; k < 8; ++k) ov[k] = (short)f2bf(acc[k]);
  *(bf16x8*)(X + r * 512 + h0) = ov;
}

// ---------- GEMM (verified): C = A[M][K] @ BT[N][K]^T, 128x128, BK=64 ----------
template <int EPI, bool TSTORE>  // EPI: 0 none, 1 +bias, 2 +bias+relu
__global__ __launch_bounds__(256, 2)
void gemm_bt(const ushort_t* __restrict__ A, const ushort_t* __restrict__ BT,
             ushort_t* __restrict__ C, const float* __restrict__ bias, int N, int K) {
  __shared__ __align__(16) ushort_t sA[128 * 64];
  __shared__ __align__(16) ushort_t sB[128 * 64];
  const int tid = threadIdx.x;
  const int lane = tid & 63;
  const int wid = tid >> 6;
  const int l15 = lane & 15, l4 = lane >> 4;
  const int wr = (wid >> 1) * 64, wc = (wid & 1) * 64;
  const size_t rowA0 = (size_t)blockIdx.x * 128;
  const size_t rowB0 = (size_t)blockIdx.y * 128;

  f32x4 acc[4][4] = {};

  for (int kt = 0; kt < K; kt += 64) {
#pragma unroll
    for (int it = 0; it < 4; ++it) {
      const int L = it * 256 + tid;
      const int row = L >> 3;
      const int c = (L & 7) ^ (row & 7);
      gld_lds16(A + (rowA0 + row) * K + kt + c * 8, sA + (size_t)L * 8);
      gld_lds16(BT + (rowB0 + row) * K + kt + c * 8, sB + (size_t)L * 8);
    }
    __syncthreads();
#pragma unroll
    for (int kk = 0; kk < 2; ++kk) {
      bf16x8 af[4], bfr[4];
#pragma unroll
      for (int mi = 0; mi < 4; ++mi) {
        const int row = wr + mi * 16 + l15;
        const int c = (kk * 4 + l4) ^ (row & 7);
        af[mi] = *(const bf16x8*)(sA + row * 64 + c * 8);
      }
#pragma unroll
      for (int ni = 0; ni < 4; ++ni) {
        const int row = wc + ni * 16 + l15;
        const int c = (kk * 4 + l4) ^ (row & 7);
        bfr[ni] = *(const bf16x8*)(sB + row * 64 + c * 8);
      }
#pragma unroll
      for (int mi = 0; mi < 4; ++mi)
#pragma unroll
        for (int ni = 0; ni < 4; ++ni)
          acc[mi][ni] = mfma16(af[mi], bfr[ni], acc[mi][ni]);
    }
    __syncthreads();
  }
#pragma unroll
  for (int ni = 0; ni < 4; ++ni) {
    const int col = (int)rowB0 + wc + ni * 16 + l15;
    float bv = 0.f;
    if (EPI > 0) bv = bias[col];
#pragma unroll
    for (int mi = 0; mi < 4; ++mi) {
      const size_t row0 = rowA0 + wr + mi * 16 + l4 * 4;
      if (TSTORE) {
        ushort4 ov;
        ov.x = f2bf(acc[mi][ni][0]);
        ov.y = f2bf(acc[mi][ni][1]);
        ov.z = f2bf(acc[mi][ni][2]);
        ov.w = f2bf(acc[mi][ni][3]);
        *(ushort4*)(C + ((row0 >> 10) * 256 + (size_t)col) * 1024 + (row0 & 1023)) = ov;
      } else {
#pragma unroll
        for (int j = 0; j < 4; ++j) {
          float v = acc[mi][ni][j] + bv;
          if (EPI == 2) v = fmaxf(v, 0.f);
          C[(row0 + j) * N + col] = f2bf(v);
        }
      }
    }
  }
}

// ---------- NEW: 256-row tile GEMM with counted-vmcnt 3-buffer pipeline --------
// BM=256 x BN(256|128), BK=32, 512 threads = 8 waves (2M x 4N).
// Per K-tile: vmcnt(LPT) [tile i landed, tile i+1 still flying] -> s_barrier ->
// stage(i+2) -> compute(i). vmcnt never drains to 0 until the last tile (T4).
template <int EPI, int BN>  // EPI: 1 +bias, 2 +bias+relu
__global__ __launch_bounds__(512, 2)
void gemm256(const ushort_t* __restrict__ A, const ushort_t* __restrict__ BT,
             ushort_t* __restrict__ C, const float* __restrict__ bias, int N, int K) {
  constexpr int ATILE = 256 * 32;          // elements per A K-tile
  constexpr int BTILE = BN * 32;
  constexpr int WN = BN / 4;               // cols per wave (64 or 32)
  constexpr int NREP = WN / 16;            // 4 or 2
  __shared__ __align__(16) ushort_t sA[3][ATILE];
  __shared__ __align__(16) ushort_t sB[3][BTILE];
  const int tid = threadIdx.x;             // 0..511
  const int lane = tid & 63;
  const int wid = tid >> 6;                // 0..7
  const int l15 = lane & 15, l4 = lane >> 4;
  const int wm = wid >> 2, wn = wid & 3;   // 2 x 4 wave grid
  const size_t rowA0 = (size_t)blockIdx.x * 256;
  const size_t rowB0 = (size_t)blockIdx.y * BN;

  f32x4 acc[8][NREP] = {};

  auto stage = [&](int buf, int kt) {
#pragma unroll
    for (int j = 0; j < 2; ++j) {          // A: 256 rows x 4 chunks = 1024 L
      const int L = j * 512 + tid;
      const int row = L >> 2;
      const int c = (L & 3) ^ (row & 3);
      gld_lds16(A + (rowA0 + row) * K + kt + c * 8, sA[buf] + (size_t)L * 8);
    }
#pragma unroll
    for (int j = 0; j < BN / 128; ++j) {   // B: BN rows x 4 chunks
      const int L = j * 512 + tid;
      const int row = L >> 2;
      const int c = (L & 3) ^ (row & 3);
      gld_lds16(BT + (rowB0 + row) * K + kt + c * 8, sB[buf] + (size_t)L * 8);
    }
  };
  auto compute = [&](int buf) {
    bf16x8 af[8], bfr[NREP];
#pragma unroll
    for (int mi = 0; mi < 8; ++mi) {
      const int row = wm * 128 + mi * 16 + l15;
      const int cs = l4 ^ (row & 3);
      af[mi] = *(const bf16x8*)(sA[buf] + row * 32 + cs * 8);
    }
#pragma unroll
    for (int ni = 0; ni < NREP; ++ni) {
      const int row = wn * WN + ni * 16 + l15;
      const int cs = l4 ^ (row & 3);
      bfr[ni] = *(const bf16x8*)(sB[buf] + row * 32 + cs * 8);
    }
#pragma unroll
    for (int mi = 0; mi < 8; ++mi)
#pragma unroll
      for (int ni = 0; ni < NREP; ++ni)
        acc[mi][ni] = mfma16(af[mi], bfr[ni], acc[mi][ni]);
  };

  const int NT = K >> 5;                   // K/32 tiles (>=16 here)
  stage(0, 0);
  stage(1, 32);
  int buf = 0;
  for (int i = 0; i < NT; ++i) {
    if (i < NT - 1) {
      if constexpr (BN == 256)
        asm volatile("s_waitcnt vmcnt(4)" ::: "memory");   // LPT=4 (A2+B2)
      else
        asm volatile("s_waitcnt vmcnt(3)" ::: "memory");   // LPT=3 (A2+B1)
    } else {
      asm volatile("s_waitcnt vmcnt(0)" ::: "memory");
    }
    __builtin_amdgcn_sched_barrier(0);
    __builtin_amdgcn_s_barrier();          // all waves: tile i visible,
    __builtin_amdgcn_sched_barrier(0);     // buf[(i+2)%3]'s readers done
    if (i + 2 < NT) {
      int nb = buf + 2; if (nb >= 3) nb -= 3;
      stage(nb, (i + 2) * 32);
    }
    compute(buf);
    if (++buf == 3) buf = 0;
  }

#pragma unroll
  for (int ni = 0; ni < NREP; ++ni) {
    const int col = (int)rowB0 + wn * WN + ni * 16 + l15;
    const float bv = bias[col];
#pragma unroll
    for (int mi = 0; mi < 8; ++mi) {
      const size_t row0 = rowA0 + wm * 128 + mi * 16 + l4 * 4;
#pragma unroll
      for (int j = 0; j < 4; ++j) {
        float v = acc[mi][ni][j] + bv;
        if (EPI == 2) v = fmaxf(v, 0.f);
        C[(row0 + j) * N + col] = f2bf(v);
      }
    }
  }
}

// ---------- flash attention (verified round-4), defer-max, batch->XCD ----------
__global__ __launch_bounds__(256, 2)
void attn_kernel(const ushort_t* __restrict__ Q, const ushort_t* __restrict__ Kb,
                 const ushort_t* __restrict__ VT, const float* __restrict__ mask,
                 ushort_t* __restrict__ Z, int colOff) {
  __shared__ __align__(16) ushort_t sK[64 * 256];   // swizzled
  __shared__ __align__(16) ushort_t sV[256 * 64];   // swizzled
  const int tid = threadIdx.x, lane = tid & 63, w = tid >> 6;
  const int l15 = lane & 15, l4 = lane >> 4;
  const int id = blockIdx.x;
  const int b = ((id >> 7) << 3) | (id & 7);
  const int qb = (id >> 3) & 15;
  const int q0 = qb * 64 + w * 16;

  bf16x8 qf[8];
  {
    const ushort_t* qrow = Q + ((size_t)b * 1024 + q0 + l15) * 256;
#pragma unroll
    for (int kk = 0; kk < 8; ++kk)
      qf[kk] = *(const bf16x8*)(qrow + kk * 32 + l4 * 8);
  }
  float m_run = -3.0e38f, l_run = 0.f;
  f32x4 o[16] = {};
  const int src0 = ((l4 & 1) << 5) + l15;  // 32*(g&1)+q
  const bool hiSel = (l4 >= 2);

  for (int t0 = 0; t0 < 1024; t0 += 64) {
#pragma unroll
    for (int it = 0; it < 8; ++it) {
      const int L = it * 256 + tid;
      const int rk = L >> 5;
      const int ck = (L & 24) | ((L ^ rk) & 7);
      gld_lds16(Kb + ((size_t)b * 1024 + t0 + rk) * 256 + ck * 8, sK + (size_t)L * 8);
      const int rv = L >> 3;
      const int cv2 = (L ^ rv) & 7;
      gld_lds16(VT + ((size_t)b * 256 + rv) * 1024 + t0 + cv2 * 8, sV + (size_t)L * 8);
    }
    __syncthreads();

    f32x4 st[4] = {};
#pragma unroll
    for (int fi = 0; fi < 4; ++fi) {
      const int row = fi * 16 + l15;
      const ushort_t* kr = sK + row * 256;
#pragma unroll
      for (int kk = 0; kk < 8; ++kk) {
        const int c = kk * 4 + l4;
        const int cs = (c & 24) | ((c ^ row) & 7);
        const bf16x8 kf = *(const bf16x8*)(kr + cs * 8);
        st[fi] = mfma16(kf, qf[kk], st[fi]);
      }
    }

    float pr[4][4];
    float tmax = -3.0e38f;
#pragma unroll
    for (int fi = 0; fi < 4; ++fi) {
      const float4 mk = *(const float4*)(mask + (size_t)b * 1024 + t0 + fi * 16 + l4 * 4);
      pr[fi][0] = st[fi][0] * 0.0625f + (mk.x * 1e6f - 1e6f);
      pr[fi][1] = st[fi][1] * 0.0625f + (mk.y * 1e6f - 1e6f);
      pr[fi][2] = st[fi][2] * 0.0625f + (mk.z * 1e6f - 1e6f);
      pr[fi][3] = st[fi][3] * 0.0625f + (mk.w * 1e6f - 1e6f);
      tmax = fmaxf(tmax, fmaxf(fmaxf(pr[fi][0], pr[fi][1]), fmaxf(pr[fi][2], pr[fi][3])));
    }
    tmax = fmaxf(tmax, __shfl_xor(tmax, 16));
    tmax = fmaxf(tmax, __shfl_xor(tmax, 32));

    if (!__all(tmax <= m_run + 8.f)) {
      const float m_new = fmaxf(m_run, tmax);
      const float alpha = __expf(m_run - m_new);
      l_run *= alpha;
      m_run = m_new;
#pragma unroll
      for (int ai = 0; ai < 16; ++ai) o[ai] *= alpha;
    }

    float rs = 0.f;
#pragma unroll
    for (int fi = 0; fi < 4; ++fi)
#pragma unroll
      for (int j = 0; j < 4; ++j) {
        pr[fi][j] = __expf(pr[fi][j] - m_run);
        rs += pr[fi][j];
      }
    rs += __shfl_xor(rs, 16);
    rs += __shfl_xor(rs, 32);
    l_run += rs;

    uint32 pk[4][2];
#pragma unroll
    for (int fi = 0; fi < 4; ++fi) {
      pk[fi][0] = pack2bf(pr[fi][0], pr[fi][1]);
      pk[fi][1] = pack2bf(pr[fi][2], pr[fi][3]);
    }
    bf16x8 pf[2];
#pragma unroll
    for (int kk2 = 0; kk2 < 2; ++kk2) {
      const uint32 a0 = __shfl(pk[2 * kk2][0], src0);
      const uint32 a1 = __shfl(pk[2 * kk2][1], src0);
      const uint32 a2 = __shfl(pk[2 * kk2][0], src0 + 16);
      const uint32 a3 = __shfl(pk[2 * kk2][1], src0 + 16);
      const uint32 b0 = __shfl(pk[2 * kk2 + 1][0], src0);
      const uint32 b1 = __shfl(pk[2 * kk2 + 1][1], src0);
      const uint32 b2 = __shfl(pk[2 * kk2 + 1][0], src0 + 16);
      const uint32 b3 = __shfl(pk[2 * kk2 + 1][1], src0 + 16);
      uint4 wv;
      wv.x = hiSel ? b0 : a0;
      wv.y = hiSel ? b1 : a1;
      wv.z = hiSel ? b2 : a2;
      wv.w = hiSel ? b3 : a3;
      pf[kk2] = __builtin_bit_cast(bf16x8, wv);
    }

#pragma unroll
    for (int ai = 0; ai < 16; ++ai) {
      const int row = ai * 16 + l15;
      const ushort_t* vr = sV + row * 64;
#pragma unroll
      for (int kk2 = 0; kk2 < 2; ++kk2) {
        const int c = (kk2 * 4 + l4) ^ (row & 7);
        const bf16x8 vf = *(const bf16x8*)(vr + c * 8);
        o[ai] = mfma16(vf, pf[kk2], o[ai]);
      }
    }
    __syncthreads();
  }

  const float inv = 1.f / l_run;
  const size_t zrow = ((size_t)b * 1024 + q0 + l15) * 512;
#pragma unroll
  for (int ai = 0; ai < 16; ++ai) {
    ushort4 ov;
    ov.x = f2bf(o[ai][0] * inv);
    ov.y = f2bf(o[ai][1] * inv);
    ov.z = f2bf(o[ai][2] * inv);
    ov.w = f2bf(o[ai][3] * inv);
    *(ushort4*)(Z + zrow + colOff + ai * 16 + l4 * 4) = ov;
  }
}

// ---------- LayerNorm(a+b) -> bf16 ; one wave per row ----------
__global__ __launch_bounds__(256)
void ln_kernel(const ushort_t* __restrict__ Xa, const ushort_t* __restrict__ Xb2,
               const float* __restrict__ g, const float* __restrict__ bb,
               ushort_t* __restrict__ O) {
  const int tid = threadIdx.x;
  const size_t r = (size_t)blockIdx.x * 4 + (tid >> 6);
  const int lane = tid & 63;
  const int h0 = lane * 8;
  const bf16x8 va = *(const bf16x8*)(Xa + r * 512 + h0);
  const bf16x8 vb = *(const bf16x8*)(Xb2 + r * 512 + h0);
  float v[8], s1 = 0.f, s2 = 0.f;
#pragma unroll
  for (int k = 0; k < 8; ++k) {
    v[k] = bf2f(va[k]) + bf2f(vb[k]);
    s1 += v[k];
    s2 += v[k] * v[k];
  }
#pragma unroll
  for (int m = 1; m < 64; m <<= 1) {
    s1 += __shfl_xor(s1, m);
    s2 += __shfl_xor(s2, m);
  }
  const float mean = s1 * (1.f / 512.f);
  const float var = s2 * (1.f / 512.f) - mean * mean;
  const float rstd = rsqrtf(var + 1e-5f);
  const float4 g0 = *(const float4*)(g + h0);
  const float4 g1 = *(const float4*)(g + h0 + 4);
  const float4 b0 = *(const float4*)(bb + h0);
  const float4 b1 = *(const float4*)(bb + h0 + 4);
  const float gg[8] = {g0.x, g0.y, g0.z, g0.w, g1.x, g1.y, g1.z, g1.w};
  const float bbv[8] = {b0.x, b0.y, b0.z, b0.w, b1.x, b1.y, b1.z, b1.w};
  bf16x8 ov;
#pragma unroll
  for (int k = 0; k < 8; ++k)
    ov[k] = (short)f2bf((v[k] - mean) * rstd * gg[k] + bbv[k]);
  *(bf16x8*)(O + r * 512 + h0) = ov;
}

// ---------- LayerNorm(a+b) then dot with Wfin + bfin -> f32 out ----------
__global__ __launch_bounds__(256)
void ln_fin_kernel(const ushort_t* __restrict__ Xa, const ushort_t* __restrict__ Xb2,
                   const float* __restrict__ g, const float* __restrict__ bb,
                   const float* __restrict__ Wfin, const float* __restrict__ bfin,
                   float* __restrict__ out) {
  const int tid = threadIdx.x;
  const size_t r = (size_t)blockIdx.x * 4 + (tid >> 6);
  const int lane = tid & 63;
  const int h0 = lane * 8;
  const bf16x8 va = *(const bf16x8*)(Xa + r * 512 + h0);
  const bf16x8 vb = *(const bf16x8*)(Xb2 + r * 512 + h0);
  float v[8], s1 = 0.f, s2 = 0.f;
#pragma unroll
  for (int k = 0; k < 8; ++k) {
    v[k] = bf2f(va[k]) + bf2f(vb[k]);
    s1 += v[k];
    s2 += v[k] * v[k];
  }
#pragma unroll
  for (int m = 1; m < 64; m <<= 1) {
    s1 += __shfl_xor(s1, m);
    s2 += __shfl_xor(s2, m);
  }
  const float mean = s1 * (1.f / 512.f);
  const float var = s2 * (1.f / 512.f) - mean * mean;
  const float rstd = rsqrtf(var + 1e-5f);
  const float4 g0 = *(const float4*)(g + h0);
  const float4 g1 = *(const float4*)(g + h0 + 4);
  const float4 b0 = *(const float4*)(bb + h0);
  const float4 b1 = *(const float4*)(bb + h0 + 4);
  const float4 w0 = *(const float4*)(Wfin + h0);
  const float4 w1 = *(const float4*)(Wfin + h0 + 4);
  const float gg[8] = {g0.x, g0.y, g0.z, g0.w, g1.x, g1.y, g1.z, g1.w};
  const float bbv[8] = {b0.x, b0.y, b0.z, b0.w, b1.x, b1.y, b1.z, b1.w};
  const float ww[8] = {w0.x, w0.y, w0.z, w0.w, w1.x, w1.y, w1.z, w1.w};
  float dot = 0.f;
#pragma unroll
  for (int k = 0; k < 8; ++k)
    dot += ((v[k] - mean) * rstd * gg[k] + bbv[k]) * ww[k];
#pragma unroll
  for (int m = 1; m < 64; m <<= 1) dot += __shfl_xor(dot, m);
  if (lane == 0) out[r] = dot + bfin[0];
}

// ---------- launch ----------
extern "C" void kernel_launch(void* const* d_in, const int* in_sizes, int n_in,
                              void* d_out, int out_size, void* d_ws, size_t ws_size,
                              hipStream_t stream) {
  (void)in_sizes; (void)n_in; (void)out_size; (void)ws_size;
  const int* cate   = (const int*)d_in[0];
  const float* cont = (const float*)d_in[1];
  const float* mask = (const float*)d_in[2];
  const float* E    = (const float*)d_in[4];
  const float* Wp   = (const float*)d_in[5];
  const float* WQ1  = (const float*)d_in[6];
  const float* WK1  = (const float*)d_in[7];
  const float* WV1  = (const float*)d_in[8];
  const float* WQ2  = (const float*)d_in[9];
  const float* WK2  = (const float*)d_in[10];
  const float* WV2  = (const float*)d_in[11];
  const float* W0   = (const float*)d_in[12];
  const float* ln1g = (const float*)d_in[13];
  const float* ln1b = (const float*)d_in[14];
  const float* Wf1  = (const float*)d_in[15];
  const float* bf1  = (const float*)d_in[16];
  const float* Wf2  = (const float*)d_in[17];
  const float* bf2  = (const float*)d_in[18];
  const float* ln2g = (const float*)d_in[19];
  const float* ln2b = (const float*)d_in[20];
  const float* Wfin = (const float*)d_in[21];
  const float* bfin = (const float*)d_in[22];
  float* out = (float*)d_out;
  char* ws = (char*)d_ws;

  // workspace layout (1 MB = 1<<20), peak ~236 MB with overlays (round-2 map)
  const size_t MB = 1ull << 20;
  ushort_t* Xb  = (ushort_t*)(ws + 0);
  ushort_t* Qb  = (ushort_t*)(ws + 64 * MB);
  ushort_t* Kb  = (ushort_t*)(ws + 96 * MB);
  ushort_t* VTb = (ushort_t*)(ws + 128 * MB);
  ushort_t* Zb  = (ushort_t*)(ws + 160 * MB);
  ushort_t* T0b = (ushort_t*)(ws + 64 * MB);
  ushort_t* H1b = (ushort_t*)(ws + 128 * MB);
  ushort_t* Gb  = (ushort_t*)(ws + 0);
  ushort_t* T1b = (ushort_t*)(ws + 64 * MB);
  const size_t OW = 224 * MB;
  ushort_t* wq1t = (ushort_t*)(ws + OW + 0);
  ushort_t* wk1t = (ushort_t*)(ws + OW + 262144);
  ushort_t* wv1t = (ushort_t*)(ws + OW + 524288);
  ushort_t* wq2t = (ushort_t*)(ws + OW + 786432);
  ushort_t* wk2t = (ushort_t*)(ws + OW + 1048576);
  ushort_t* wv2t = (ushort_t*)(ws + OW + 1310720);
  ushort_t* w0t  = (ushort_t*)(ws + OW + 1572864);
  ushort_t* wf1t = (ushort_t*)(ws + OW + 2097152);
  ushort_t* wf2t = (ushort_t*)(ws + OW + 4194304);
  ushort_t* epb  = (ushort_t*)(ws + OW + 6291456);
  float*    peb  = (float*)   (ws + OW + 10485760);

  const dim3 blk(256);
  // prep
  transpose_w<<<dim3(16, 8), blk, 0, stream>>>(WQ1, wq1t, 512, 256);
  transpose_w<<<dim3(16, 8), blk, 0, stream>>>(WK1, wk1t, 512, 256);
  transpose_w<<<dim3(16, 8), blk, 0, stream>>>(WV1, wv1t, 512, 256);
  transpose_w<<<dim3(16, 8), blk, 0, stream>>>(WQ2, wq2t, 512, 256);
  transpose_w<<<dim3(16, 8), blk, 0, stream>>>(WK2, wk2t, 512, 256);
  transpose_w<<<dim3(16, 8), blk, 0, stream>>>(WV2, wv2t, 512, 256);
  transpose_w<<<dim3(16, 16), blk, 0, stream>>>(W0, w0t, 512, 512);
  transpose_w<<<dim3(16, 64), blk, 0, stream>>>(Wf1, wf1t, 512, 2048);
  transpose_w<<<dim3(64, 16), blk, 0, stream>>>(Wf2, wf2t, 2048, 512);
  ep_kernel<<<4000, blk, 0, stream>>>(E, Wp, epb);
  pe_kernel<<<1024, blk, 0, stream>>>(peb);
  x_kernel<<<16384, blk, 0, stream>>>(cate, cont, Wp, epb, peb, Xb);
  // branch 1 (V projection stores transposed directly into VT)
  gemm_bt<0, false><<<dim3(512, 2), blk, 0, stream>>>(Xb, wq1t, Qb, nullptr, 256, 512);
  gemm_bt<0, false><<<dim3(512, 2), blk, 0, stream>>>(Xb, wk1t, Kb, nullptr, 256, 512);
  gemm_bt<0, true><<<dim3(512, 2), blk, 0, stream>>>(Xb, wv1t, VTb, nullptr, 256, 512);
  attn_kernel<<<dim3(1024), blk, 0, stream>>>(Qb, Kb, VTb, mask, Zb, 0);
  // branch 2 (reuse buffers)
  gemm_bt<0, false><<<dim3(512, 2), blk, 0, stream>>>(Xb, wq2t, Qb, nullptr, 256, 512);
  gemm_bt<0, false><<<dim3(512, 2), blk, 0, stream>>>(Xb, wk2t, Kb, nullptr, 256, 512);
  gemm_bt<0, true><<<dim3(512, 2), blk, 0, stream>>>(Xb, wv2t, VTb, nullptr, 256, 512);
  attn_kernel<<<dim3(1024), blk, 0, stream>>>(Qb, Kb, VTb, mask, Zb, 256);
  // W0 + LN1
  gemm_bt<0, false><<<dim3(512, 4), blk, 0, stream>>>(Zb, w0t, T0b, nullptr, 512, 512);
  ln_kernel<<<16384, blk, 0, stream>>>(Xb, T0b, ln1g, ln1b, H1b);
  // FF in 4 row-chunks of 16384 — NEW gemm256 (counted-vmcnt pipeline)
  for (int rc = 0; rc < 4; ++rc) {
    const ushort_t* h1c = H1b + (size_t)rc * 16384 * 512;
    ushort_t* t1c = T1b + (size_t)rc * 16384 * 512;
    gemm256<2, 256><<<dim3(64, 8), dim3(512), 0, stream>>>(h1c, wf1t, Gb, bf1, 2048, 512);
    gemm256<1, 128><<<dim3(64, 4), dim3(512), 0, stream>>>(Gb, wf2t, t1c, bf2, 512, 2048);
  }
  ln_fin_kernel<<<16384, blk, 0, stream>>>(H1b, T1b, ln2g, ln2b, Wfin, bfin, out);
}

// Round 9
// 994.042 us; speedup vs baseline: 1.1974x; 1.1974x over previous
//
// SelfAttention6 — MI355X bf16 MFMA, round 9:
//  - FF reverted to verified gemm_bt (gemm256 was 1-block/CU, regressed)
//  - gemm_bt: __launch_bounds__(256,3) -> 3 blocks/CU (was 2), VGPR cap 170
//  - attn: round-4 exact + s_setprio(1) around MFMA clusters (T5, +4-7% attn)
//  - 9 transpose_w launches fused into one batched transpose_all launch
// B=64 S=1024 H=512 A=256 F=2048 NCATE=4 VOCAB=1000 EMB=64 NCONT=4
#include <hip/hip_runtime.h>

typedef unsigned short ushort_t;
typedef unsigned int uint32;
typedef float f32x4 __attribute__((ext_vector_type(4)));
typedef short bf16x8 __attribute__((ext_vector_type(8)));

// ---------- helpers ----------
__device__ __forceinline__ float bf2f(short u) {
  union { uint32 u32; float f; } cv;
  cv.u32 = ((uint32)(ushort_t)u) << 16;
  return cv.f;
}
__device__ __forceinline__ ushort_t f2bf(float f) {
  union { float f; uint32 u; } cv; cv.f = f;
  return (ushort_t)((cv.u + 0x7fffu + ((cv.u >> 16) & 1u)) >> 16);  // RNE
}
__device__ __forceinline__ uint32 pack2bf(float lo, float hi) {
  return (uint32)f2bf(lo) | ((uint32)f2bf(hi) << 16);
}
__device__ __forceinline__ f32x4 mfma16(bf16x8 a, bf16x8 b, f32x4 c) {
  return __builtin_amdgcn_mfma_f32_16x16x32_bf16(a, b, c, 0, 0, 0);
}
__device__ __forceinline__ void gld_lds16(const ushort_t* g, ushort_t* l) {
  __builtin_amdgcn_global_load_lds(
      (const __attribute__((address_space(1))) void*)g,
      (__attribute__((address_space(3))) void*)l, 16, 0, 0);
}

// ---------- batched weight transpose+cast: all 9 weights in one launch -------
// tile ranges: [0,768) QKV1/2 (6 x 128 tiles, 512x256); [768,1024) W0 512x512;
// [1024,2048) Wf1 512x2048; [2048,3072) Wf2 2048x512.
struct TPtrs {
  const float* s[9];
  ushort_t* d[9];
};
__global__ __launch_bounds__(256)
void transpose_all(TPtrs p) {
  const int id = blockIdx.x;
  const float* S;
  ushort_t* D;
  int K, N, lt;
  if (id < 768) {
    const int wsel = id >> 7;
    lt = id & 127; S = p.s[wsel]; D = p.d[wsel]; K = 512; N = 256;
  } else if (id < 1024) {
    lt = id - 768; S = p.s[6]; D = p.d[6]; K = 512; N = 512;
  } else if (id < 2048) {
    lt = id - 1024; S = p.s[7]; D = p.d[7]; K = 512; N = 2048;
  } else {
    lt = id - 2048; S = p.s[8]; D = p.d[8]; K = 2048; N = 512;
  }
  const int ntn = N >> 5;
  const int k0 = (lt / ntn) * 32, n0 = (lt % ntn) * 32;
  __shared__ float sm[32][33];
  const int tx = threadIdx.x & 31, ty = threadIdx.x >> 5;
#pragma unroll
  for (int i = 0; i < 4; ++i)
    sm[ty + i * 8][tx] = S[(size_t)(k0 + ty + i * 8) * N + n0 + tx];
  __syncthreads();
#pragma unroll
  for (int i = 0; i < 4; ++i)
    D[(size_t)(n0 + ty + i * 8) * K + k0 + tx] = f2bf(sm[tx][ty + i * 8]);
}

// ---------- EP[c,v,h] = sum_e E[c,v,e]*Wp[c*64+e, h]  (bf16 out) ----------
__global__ __launch_bounds__(256)
void ep_kernel(const float* __restrict__ E, const float* __restrict__ Wp,
               ushort_t* __restrict__ EP) {
  const int cv = blockIdx.x;          // 0..3999
  const int c = cv / 1000;
  __shared__ float se[64];
  if (threadIdx.x < 64) se[threadIdx.x] = E[(size_t)cv * 64 + threadIdx.x];
  __syncthreads();
  const float* wrow = Wp + (size_t)c * 64 * 512;
  for (int h = threadIdx.x; h < 512; h += 256) {
    float acc = 0.f;
#pragma unroll
    for (int e = 0; e < 64; ++e) acc += se[e] * wrow[(size_t)e * 512 + h];
    EP[(size_t)cv * 512 + h] = f2bf(acc);
  }
}

// ---------- positional-encoding table PE[1024][512] f32 ----------
__global__ __launch_bounds__(256)
void pe_kernel(float* __restrict__ PE) {
  const int id = blockIdx.x * 256 + threadIdx.x;  // 262144
  const int s = id >> 8, i = id & 255;
  const float ang = (float)s * exp2f(-(float)i * (13.287712379549449f / 256.0f));
  PE[(size_t)s * 512 + 2 * i] = sinf(ang);
  PE[(size_t)s * 512 + 2 * i + 1] = cosf(ang);
}

// ---------- x = gather(EP) + cont@Wp_tail + PE  -> bf16 [65536][512] ----------
__global__ __launch_bounds__(256)
void x_kernel(const int* __restrict__ cate, const float* __restrict__ cont,
              const float* __restrict__ Wp, const ushort_t* __restrict__ EP,
              const float* __restrict__ PE, ushort_t* __restrict__ X) {
  const int tid = threadIdx.x;
  const size_t r = (size_t)blockIdx.x * 4 + (tid >> 6);
  const int lane = tid & 63;
  const int h0 = lane * 8;
  const int s = (int)(r & 1023);
  float acc[8];
  const float4 p0 = *(const float4*)(PE + (size_t)s * 512 + h0);
  const float4 p1 = *(const float4*)(PE + (size_t)s * 512 + h0 + 4);
  acc[0] = p0.x; acc[1] = p0.y; acc[2] = p0.z; acc[3] = p0.w;
  acc[4] = p1.x; acc[5] = p1.y; acc[6] = p1.z; acc[7] = p1.w;
#pragma unroll
  for (int c = 0; c < 4; ++c) {
    const int idx = cate[r * 4 + c];
    const bf16x8 e8 = *(const bf16x8*)(EP + ((size_t)(c * 1000 + idx)) * 512 + h0);
#pragma unroll
    for (int k = 0; k < 8; ++k) acc[k] += bf2f(e8[k]);
  }
#pragma unroll
  for (int j = 0; j < 4; ++j) {
    const float cj = cont[r * 4 + j];
    const float4 w0 = *(const float4*)(Wp + (size_t)(256 + j) * 512 + h0);
    const float4 w1 = *(const float4*)(Wp + (size_t)(256 + j) * 512 + h0 + 4);
    acc[0] += cj * w0.x; acc[1] += cj * w0.y; acc[2] += cj * w0.z; acc[3] += cj * w0.w;
    acc[4] += cj * w1.x; acc[5] += cj * w1.y; acc[6] += cj * w1.z; acc[7] += cj * w1.w;
  }
  bf16x8 ov;
#pragma unroll
  for (int k = 0; k < 8; ++k) ov[k] = (short)f2bf(acc[k]);
  *(bf16x8*)(X + r * 512 + h0) = ov;
}

// ---------- GEMM: C = A[M][K] @ BT[N][K]^T (+bias/relu; optional V^T store) ----
// 128x128 tile, BK=64, 4 waves (2x2), 16x16x32 MFMA, global_load_lds staging,
// XOR-swizzled LDS. launch_bounds(256,3): 3 blocks/CU (96KB LDS, VGPR<=170).
template <int EPI, bool TSTORE>  // EPI: 0 none, 1 +bias, 2 +bias+relu
__global__ __launch_bounds__(256, 3)
void gemm_bt(const ushort_t* __restrict__ A, const ushort_t* __restrict__ BT,
             ushort_t* __restrict__ C, const float* __restrict__ bias, int N, int K) {
  __shared__ __align__(16) ushort_t sA[128 * 64];
  __shared__ __align__(16) ushort_t sB[128 * 64];
  const int tid = threadIdx.x;
  const int lane = tid & 63;
  const int wid = tid >> 6;
  const int l15 = lane & 15, l4 = lane >> 4;
  const int wr = (wid >> 1) * 64, wc = (wid & 1) * 64;
  const size_t rowA0 = (size_t)blockIdx.x * 128;
  const size_t rowB0 = (size_t)blockIdx.y * 128;

  f32x4 acc[4][4] = {};

  for (int kt = 0; kt < K; kt += 64) {
#pragma unroll
    for (int it = 0; it < 4; ++it) {
      const int L = it * 256 + tid;
      const int row = L >> 3;
      const int c = (L & 7) ^ (row & 7);
      gld_lds16(A + (rowA0 + row) * K + kt + c * 8, sA + (size_t)L * 8);
      gld_lds16(BT + (rowB0 + row) * K + kt + c * 8, sB + (size_t)L * 8);
    }
    __syncthreads();
#pragma unroll
    for (int kk = 0; kk < 2; ++kk) {
      bf16x8 af[4], bfr[4];
#pragma unroll
      for (int mi = 0; mi < 4; ++mi) {
        const int row = wr + mi * 16 + l15;
        const int c = (kk * 4 + l4) ^ (row & 7);
        af[mi] = *(const bf16x8*)(sA + row * 64 + c * 8);
      }
#pragma unroll
      for (int ni = 0; ni < 4; ++ni) {
        const int row = wc + ni * 16 + l15;
        const int c = (kk * 4 + l4) ^ (row & 7);
        bfr[ni] = *(const bf16x8*)(sB + row * 64 + c * 8);
      }
#pragma unroll
      for (int mi = 0; mi < 4; ++mi)
#pragma unroll
        for (int ni = 0; ni < 4; ++ni)
          acc[mi][ni] = mfma16(af[mi], bfr[ni], acc[mi][ni]);
    }
    __syncthreads();
  }
#pragma unroll
  for (int ni = 0; ni < 4; ++ni) {
    const int col = (int)rowB0 + wc + ni * 16 + l15;
    float bv = 0.f;
    if (EPI > 0) bv = bias[col];
#pragma unroll
    for (int mi = 0; mi < 4; ++mi) {
      const size_t row0 = rowA0 + wr + mi * 16 + l4 * 4;
      if (TSTORE) {
        ushort4 ov;
        ov.x = f2bf(acc[mi][ni][0]);
        ov.y = f2bf(acc[mi][ni][1]);
        ov.z = f2bf(acc[mi][ni][2]);
        ov.w = f2bf(acc[mi][ni][3]);
        *(ushort4*)(C + ((row0 >> 10) * 256 + (size_t)col) * 1024 + (row0 & 1023)) = ov;
      } else {
#pragma unroll
        for (int j = 0; j < 4; ++j) {
          float v = acc[mi][ni][j] + bv;
          if (EPI == 2) v = fmaxf(v, 0.f);
          C[(row0 + j) * N + col] = f2bf(v);
        }
      }
    }
  }
}

// ---------- flash attention (round-4 verified) + setprio(T5) ----------
__global__ __launch_bounds__(256, 2)
void attn_kernel(const ushort_t* __restrict__ Q, const ushort_t* __restrict__ Kb,
                 const ushort_t* __restrict__ VT, const float* __restrict__ mask,
                 ushort_t* __restrict__ Z, int colOff) {
  __shared__ __align__(16) ushort_t sK[64 * 256];   // swizzled
  __shared__ __align__(16) ushort_t sV[256 * 64];   // swizzled
  const int tid = threadIdx.x, lane = tid & 63, w = tid >> 6;
  const int l15 = lane & 15, l4 = lane >> 4;
  const int id = blockIdx.x;
  const int b = ((id >> 7) << 3) | (id & 7);
  const int qb = (id >> 3) & 15;
  const int q0 = qb * 64 + w * 16;

  bf16x8 qf[8];
  {
    const ushort_t* qrow = Q + ((size_t)b * 1024 + q0 + l15) * 256;
#pragma unroll
    for (int kk = 0; kk < 8; ++kk)
      qf[kk] = *(const bf16x8*)(qrow + kk * 32 + l4 * 8);
  }
  float m_run = -3.0e38f, l_run = 0.f;
  f32x4 o[16] = {};
  const int src0 = ((l4 & 1) << 5) + l15;  // 32*(g&1)+q
  const bool hiSel = (l4 >= 2);

  for (int t0 = 0; t0 < 1024; t0 += 64) {
#pragma unroll
    for (int it = 0; it < 8; ++it) {
      const int L = it * 256 + tid;
      const int rk = L >> 5;
      const int ck = (L & 24) | ((L ^ rk) & 7);
      gld_lds16(Kb + ((size_t)b * 1024 + t0 + rk) * 256 + ck * 8, sK + (size_t)L * 8);
      const int rv = L >> 3;
      const int cv2 = (L ^ rv) & 7;
      gld_lds16(VT + ((size_t)b * 256 + rv) * 1024 + t0 + cv2 * 8, sV + (size_t)L * 8);
    }
    __syncthreads();

    __builtin_amdgcn_s_setprio(1);
    f32x4 st[4] = {};
#pragma unroll
    for (int fi = 0; fi < 4; ++fi) {
      const int row = fi * 16 + l15;
      const ushort_t* kr = sK + row * 256;
#pragma unroll
      for (int kk = 0; kk < 8; ++kk) {
        const int c = kk * 4 + l4;
        const int cs = (c & 24) | ((c ^ row) & 7);
        const bf16x8 kf = *(const bf16x8*)(kr + cs * 8);
        st[fi] = mfma16(kf, qf[kk], st[fi]);
      }
    }
    __builtin_amdgcn_s_setprio(0);

    float pr[4][4];
    float tmax = -3.0e38f;
#pragma unroll
    for (int fi = 0; fi < 4; ++fi) {
      const float4 mk = *(const float4*)(mask + (size_t)b * 1024 + t0 + fi * 16 + l4 * 4);
      pr[fi][0] = st[fi][0] * 0.0625f + (mk.x * 1e6f - 1e6f);
      pr[fi][1] = st[fi][1] * 0.0625f + (mk.y * 1e6f - 1e6f);
      pr[fi][2] = st[fi][2] * 0.0625f + (mk.z * 1e6f - 1e6f);
      pr[fi][3] = st[fi][3] * 0.0625f + (mk.w * 1e6f - 1e6f);
      tmax = fmaxf(tmax, fmaxf(fmaxf(pr[fi][0], pr[fi][1]), fmaxf(pr[fi][2], pr[fi][3])));
    }
    tmax = fmaxf(tmax, __shfl_xor(tmax, 16));
    tmax = fmaxf(tmax, __shfl_xor(tmax, 32));

    if (!__all(tmax <= m_run + 8.f)) {
      const float m_new = fmaxf(m_run, tmax);
      const float alpha = __expf(m_run - m_new);
      l_run *= alpha;
      m_run = m_new;
#pragma unroll
      for (int ai = 0; ai < 16; ++ai) o[ai] *= alpha;
    }

    float rs = 0.f;
#pragma unroll
    for (int fi = 0; fi < 4; ++fi)
#pragma unroll
      for (int j = 0; j < 4; ++j) {
        pr[fi][j] = __expf(pr[fi][j] - m_run);
        rs += pr[fi][j];
      }
    rs += __shfl_xor(rs, 16);
    rs += __shfl_xor(rs, 32);
    l_run += rs;

    uint32 pk[4][2];
#pragma unroll
    for (int fi = 0; fi < 4; ++fi) {
      pk[fi][0] = pack2bf(pr[fi][0], pr[fi][1]);
      pk[fi][1] = pack2bf(pr[fi][2], pr[fi][3]);
    }
    bf16x8 pf[2];
#pragma unroll
    for (int kk2 = 0; kk2 < 2; ++kk2) {
      const uint32 a0 = __shfl(pk[2 * kk2][0], src0);
      const uint32 a1 = __shfl(pk[2 * kk2][1], src0);
      const uint32 a2 = __shfl(pk[2 * kk2][0], src0 + 16);
      const uint32 a3 = __shfl(pk[2 * kk2][1], src0 + 16);
      const uint32 b0 = __shfl(pk[2 * kk2 + 1][0], src0);
      const uint32 b1 = __shfl(pk[2 * kk2 + 1][1], src0);
      const uint32 b2 = __shfl(pk[2 * kk2 + 1][0], src0 + 16);
      const uint32 b3 = __shfl(pk[2 * kk2 + 1][1], src0 + 16);
      uint4 wv;
      wv.x = hiSel ? b0 : a0;
      wv.y = hiSel ? b1 : a1;
      wv.z = hiSel ? b2 : a2;
      wv.w = hiSel ? b3 : a3;
      pf[kk2] = __builtin_bit_cast(bf16x8, wv);
    }

    __builtin_amdgcn_s_setprio(1);
#pragma unroll
    for (int ai = 0; ai < 16; ++ai) {
      const int row = ai * 16 + l15;
      const ushort_t* vr = sV + row * 64;
#pragma unroll
      for (int kk2 = 0; kk2 < 2; ++kk2) {
        const int c = (kk2 * 4 + l4) ^ (row & 7);
        const bf16x8 vf = *(const bf16x8*)(vr + c * 8);
        o[ai] = mfma16(vf, pf[kk2], o[ai]);
      }
    }
    __builtin_amdgcn_s_setprio(0);
    __syncthreads();
  }

  const float inv = 1.f / l_run;
  const size_t zrow = ((size_t)b * 1024 + q0 + l15) * 512;
#pragma unroll
  for (int ai = 0; ai < 16; ++ai) {
    ushort4 ov;
    ov.x = f2bf(o[ai][0] * inv);
    ov.y = f2bf(o[ai][1] * inv);
    ov.z = f2bf(o[ai][2] * inv);
    ov.w = f2bf(o[ai][3] * inv);
    *(ushort4*)(Z + zrow + colOff + ai * 16 + l4 * 4) = ov;
  }
}

// ---------- LayerNorm(a+b) -> bf16 ; one wave per row ----------
__global__ __launch_bounds__(256)
void ln_kernel(const ushort_t* __restrict__ Xa, const ushort_t* __restrict__ Xb2,
               const float* __restrict__ g, const float* __restrict__ bb,
               ushort_t* __restrict__ O) {
  const int tid = threadIdx.x;
  const size_t r = (size_t)blockIdx.x * 4 + (tid >> 6);
  const int lane = tid & 63;
  const int h0 = lane * 8;
  const bf16x8 va = *(const bf16x8*)(Xa + r * 512 + h0);
  const bf16x8 vb = *(const bf16x8*)(Xb2 + r * 512 + h0);
  float v[8], s1 = 0.f, s2 = 0.f;
#pragma unroll
  for (int k = 0; k < 8; ++k) {
    v[k] = bf2f(va[k]) + bf2f(vb[k]);
    s1 += v[k];
    s2 += v[k] * v[k];
  }
#pragma unroll
  for (int m = 1; m < 64; m <<= 1) {
    s1 += __shfl_xor(s1, m);
    s2 += __shfl_xor(s2, m);
  }
  const float mean = s1 * (1.f / 512.f);
  const float var = s2 * (1.f / 512.f) - mean * mean;
  const float rstd = rsqrtf(var + 1e-5f);
  const float4 g0 = *(const float4*)(g + h0);
  const float4 g1 = *(const float4*)(g + h0 + 4);
  const float4 b0 = *(const float4*)(bb + h0);
  const float4 b1 = *(const float4*)(bb + h0 + 4);
  const float gg[8] = {g0.x, g0.y, g0.z, g0.w, g1.x, g1.y, g1.z, g1.w};
  const float bbv[8] = {b0.x, b0.y, b0.z, b0.w, b1.x, b1.y, b1.z, b1.w};
  bf16x8 ov;
#pragma unroll
  for (int k = 0; k < 8; ++k)
    ov[k] = (short)f2bf((v[k] - mean) * rstd * gg[k] + bbv[k]);
  *(bf16x8*)(O + r * 512 + h0) = ov;
}

// ---------- LayerNorm(a+b) then dot with Wfin + bfin -> f32 out ----------
__global__ __launch_bounds__(256)
void ln_fin_kernel(const ushort_t* __restrict__ Xa, const ushort_t* __restrict__ Xb2,
                   const float* __restrict__ g, const float* __restrict__ bb,
                   const float* __restrict__ Wfin, const float* __restrict__ bfin,
                   float* __restrict__ out) {
  const int tid = threadIdx.x;
  const size_t r = (size_t)blockIdx.x * 4 + (tid >> 6);
  const int lane = tid & 63;
  const int h0 = lane * 8;
  const bf16x8 va = *(const bf16x8*)(Xa + r * 512 + h0);
  const bf16x8 vb = *(const bf16x8*)(Xb2 + r * 512 + h0);
  float v[8], s1 = 0.f, s2 = 0.f;
#pragma unroll
  for (int k = 0; k < 8; ++k) {
    v[k] = bf2f(va[k]) + bf2f(vb[k]);
    s1 += v[k];
    s2 += v[k] * v[k];
  }
#pragma unroll
  for (int m = 1; m < 64; m <<= 1) {
    s1 += __shfl_xor(s1, m);
    s2 += __shfl_xor(s2, m);
  }
  const float mean = s1 * (1.f / 512.f);
  const float var = s2 * (1.f / 512.f) - mean * mean;
  const float rstd = rsqrtf(var + 1e-5f);
  const float4 g0 = *(const float4*)(g + h0);
  const float4 g1 = *(const float4*)(g + h0 + 4);
  const float4 b0 = *(const float4*)(bb + h0);
  const float4 b1 = *(const float4*)(bb + h0 + 4);
  const float4 w0 = *(const float4*)(Wfin + h0);
  const float4 w1 = *(const float4*)(Wfin + h0 + 4);
  const float gg[8] = {g0.x, g0.y, g0.z, g0.w, g1.x, g1.y, g1.z, g1.w};
  const float bbv[8] = {b0.x, b0.y, b0.z, b0.w, b1.x, b1.y, b1.z, b1.w};
  const float ww[8] = {w0.x, w0.y, w0.z, w0.w, w1.x, w1.y, w1.z, w1.w};
  float dot = 0.f;
#pragma unroll
  for (int k = 0; k < 8; ++k)
    dot += ((v[k] - mean) * rstd * gg[k] + bbv[k]) * ww[k];
#pragma unroll
  for (int m = 1; m < 64; m <<= 1) dot += __shfl_xor(dot, m);
  if (lane == 0) out[r] = dot + bfin[0];
}

// ---------- launch ----------
extern "C" void kernel_launch(void* const* d_in, const int* in_sizes, int n_in,
                              void* d_out, int out_size, void* d_ws, size_t ws_size,
                              hipStream_t stream) {
  (void)in_sizes; (void)n_in; (void)out_size; (void)ws_size;
  const int* cate   = (const int*)d_in[0];
  const float* cont = (const float*)d_in[1];
  const float* mask = (const float*)d_in[2];
  const float* E    = (const float*)d_in[4];
  const float* Wp   = (const float*)d_in[5];
  const float* WQ1  = (const float*)d_in[6];
  const float* WK1  = (const float*)d_in[7];
  const float* WV1  = (const float*)d_in[8];
  const float* WQ2  = (const float*)d_in[9];
  const float* WK2  = (const float*)d_in[10];
  const float* WV2  = (const float*)d_in[11];
  const float* W0   = (const float*)d_in[12];
  const float* ln1g = (const float*)d_in[13];
  const float* ln1b = (const float*)d_in[14];
  const float* Wf1  = (const float*)d_in[15];
  const float* bf1  = (const float*)d_in[16];
  const float* Wf2  = (const float*)d_in[17];
  const float* bf2  = (const float*)d_in[18];
  const float* ln2g = (const float*)d_in[19];
  const float* ln2b = (const float*)d_in[20];
  const float* Wfin = (const float*)d_in[21];
  const float* bfin = (const float*)d_in[22];
  float* out = (float*)d_out;
  char* ws = (char*)d_ws;

  // workspace layout (1 MB = 1<<20), peak ~236 MB with overlays (round-2 map)
  const size_t MB = 1ull << 20;
  ushort_t* Xb  = (ushort_t*)(ws + 0);
  ushort_t* Qb  = (ushort_t*)(ws + 64 * MB);
  ushort_t* Kb  = (ushort_t*)(ws + 96 * MB);
  ushort_t* VTb = (ushort_t*)(ws + 128 * MB);
  ushort_t* Zb  = (ushort_t*)(ws + 160 * MB);
  ushort_t* T0b = (ushort_t*)(ws + 64 * MB);
  ushort_t* H1b = (ushort_t*)(ws + 128 * MB);
  ushort_t* Gb  = (ushort_t*)(ws + 0);
  ushort_t* T1b = (ushort_t*)(ws + 64 * MB);
  const size_t OW = 224 * MB;
  ushort_t* wq1t = (ushort_t*)(ws + OW + 0);
  ushort_t* wk1t = (ushort_t*)(ws + OW + 262144);
  ushort_t* wv1t = (ushort_t*)(ws + OW + 524288);
  ushort_t* wq2t = (ushort_t*)(ws + OW + 786432);
  ushort_t* wk2t = (ushort_t*)(ws + OW + 1048576);
  ushort_t* wv2t = (ushort_t*)(ws + OW + 1310720);
  ushort_t* w0t  = (ushort_t*)(ws + OW + 1572864);
  ushort_t* wf1t = (ushort_t*)(ws + OW + 2097152);
  ushort_t* wf2t = (ushort_t*)(ws + OW + 4194304);
  ushort_t* epb  = (ushort_t*)(ws + OW + 6291456);
  float*    peb  = (float*)   (ws + OW + 10485760);

  const dim3 blk(256);
  // prep: all 9 weight transposes in one launch
  TPtrs tp;
  tp.s[0] = WQ1; tp.s[1] = WK1; tp.s[2] = WV1;
  tp.s[3] = WQ2; tp.s[4] = WK2; tp.s[5] = WV2;
  tp.s[6] = W0;  tp.s[7] = Wf1; tp.s[8] = Wf2;
  tp.d[0] = wq1t; tp.d[1] = wk1t; tp.d[2] = wv1t;
  tp.d[3] = wq2t; tp.d[4] = wk2t; tp.d[5] = wv2t;
  tp.d[6] = w0t;  tp.d[7] = wf1t; tp.d[8] = wf2t;
  transpose_all<<<dim3(3072), blk, 0, stream>>>(tp);
  ep_kernel<<<4000, blk, 0, stream>>>(E, Wp, epb);
  pe_kernel<<<1024, blk, 0, stream>>>(peb);
  x_kernel<<<16384, blk, 0, stream>>>(cate, cont, Wp, epb, peb, Xb);
  // branch 1 (V projection stores transposed directly into VT)
  gemm_bt<0, false><<<dim3(512, 2), blk, 0, stream>>>(Xb, wq1t, Qb, nullptr, 256, 512);
  gemm_bt<0, false><<<dim3(512, 2), blk, 0, stream>>>(Xb, wk1t, Kb, nullptr, 256, 512);
  gemm_bt<0, true><<<dim3(512, 2), blk, 0, stream>>>(Xb, wv1t, VTb, nullptr, 256, 512);
  attn_kernel<<<dim3(1024), blk, 0, stream>>>(Qb, Kb, VTb, mask, Zb, 0);
  // branch 2 (reuse buffers)
  gemm_bt<0, false><<<dim3(512, 2), blk, 0, stream>>>(Xb, wq2t, Qb, nullptr, 256, 512);
  gemm_bt<0, false><<<dim3(512, 2), blk, 0, stream>>>(Xb, wk2t, Kb, nullptr, 256, 512);
  gemm_bt<0, true><<<dim3(512, 2), blk, 0, stream>>>(Xb, wv2t, VTb, nullptr, 256, 512);
  attn_kernel<<<dim3(1024), blk, 0, stream>>>(Qb, Kb, VTb, mask, Zb, 256);
  // W0 + LN1
  gemm_bt<0, false><<<dim3(512, 4), blk, 0, stream>>>(Zb, w0t, T0b, nullptr, 512, 512);
  ln_kernel<<<16384, blk, 0, stream>>>(Xb, T0b, ln1g, ln1b, H1b);
  // FF in 4 row-chunks of 16384 (G chunk = 64MB, overlays dead X)
  for (int rc = 0; rc < 4; ++rc) {
    const ushort_t* h1c = H1b + (size_t)rc * 16384 * 512;
    ushort_t* t1c = T1b + (size_t)rc * 16384 * 512;
    gemm_bt<2, false><<<dim3(128, 16), blk, 0, stream>>>(h1c, wf1t, Gb, bf1, 2048, 512);
    gemm_bt<1, false><<<dim3(128, 4), blk, 0, stream>>>(Gb, wf2t, t1c, bf2, 512, 2048);
  }
  ln_fin_kernel<<<16384, blk, 0, stream>>>(H1b, T1b, ln2g, ln2b, Wfin, bfin, out);
}